// Round 6
// baseline (73.929 us; speedup 1.0000x reference)
//
#include <hip/hip_runtime.h>

// Ball query via 5x5x5 uniform grid + per-batch counting sort + per-wave hit
// bitmap. B=4, N1=2048 queries, N2=8192 keys, K=64, r=0.1 (cell = 0.2 = 2r,
// so a query ball overlaps at most a 2x2x2 octant of cells).
//
// R6: TWO dispatches, no cross-block coordination. Same shape as R5 but the
// build kernel's two serialization points are fixed:
//   - privatized hist: 8 sub-histograms (one per 128-thread group) cut
//     same-address LDS atomic serialization 8x; reduced by threads 0..124.
//   - staged scatter: threads first CLAIM final slots for their 8 register-
//     held keys via LDS cursor atomics, then 4 passes of {LDS-scatter keys
//     with slot in [p*2048,(p+1)*2048) into a 32KB stage -> barrier ->
//     coalesced dwordx4 dump of the contiguous run}. R5 instead issued 8192
//     scattered 16B global stores per block from only 4 CUs (64 transactions
//     per wave-store at ~200cy, 16 waves/CU to hide it) — that was the
//     +6..9us vs R0's hist+scatter.
// Query kernel: verified R0 body, unchanged.
//
// Ledger (dur_us ~= 40us ws-poison + ~4us fixed + kernels + inter-node gaps):
//   R0 3-node hist/scatter/query: 68.2
//   R1 fuse-by-redundancy:        76.1
//   R2 cg::grid.sync:            300.2
//   R3 agent-scope flag handshake:78.8
//   R4 single-node brute force:   96.2  (52us kernel, 16x the work)
//   R5 2-node, naive 4-blk build: 72.5  (scattered stores from 4 CUs)

constexpr int   K    = 64;
constexpr float R2   = 0.01f;   // 0.1^2
constexpr int   B    = 4;
constexpr int   N1   = 2048;
constexpr int   N2   = 8192;
constexpr int   GC   = 5;                 // grid cells per dim
constexpr int   NCELL = GC * GC * GC;     // 125
constexpr float INVCELL = 5.0f;           // 1 / 0.2
constexpr int   KPT  = N2 / 1024;         // keys per build thread = 8
constexpr int   NHIST = 8;                // privatized hist copies
constexpr int   CHUNK = 2048;             // staged-output run length

// ---------------- workspace layout ----------------
// [0, 512KB) : sorted float4 [B*N2]
// then       : cell_start [B*(NCELL+1)] ints
constexpr size_t SORTED_BYTES = (size_t)B * N2 * 16;
constexpr size_t CS_BYTES     = (size_t)B * (NCELL + 1) * 4;
constexpr size_t WS_NEEDED    = SORTED_BYTES + CS_BYTES;

__device__ __forceinline__ int cell_of(float v) {
    int c = (int)(v * INVCELL);
    return c < 0 ? 0 : (c > GC - 1 ? GC - 1 : c);
}

// ---------------- pass 1: per-batch block-local build ----------------
__global__ __launch_bounds__(1024) void build_kernel(
    const float* __restrict__ key,       // [B*N2, 3]
    int* __restrict__ cell_start,        // [B, NCELL+1]
    float4* __restrict__ sorted)         // [B*N2]
{
    __shared__ int    h8[NHIST][128];    // privatized hists (padded rows)
    __shared__ int    sbuf[128];         // scan buffer
    __shared__ int    cursor[NCELL];     // slot-claim cursors
    __shared__ float4 stage[CHUNK];      // 32KB coalescing stage

    const int b = blockIdx.x;            // batch 0..3
    const int t = threadIdx.x;           // 0..1023
    const int g = t >> 7;                // hist copy 0..7

    if (t < 128) {
        #pragma unroll
        for (int i = 0; i < NHIST; ++i) h8[i][t] = 0;
    }
    __syncthreads();

    // ---- hist: 8 coalesced keys per thread, coords kept in registers ----
    const float* kb = key + (size_t)b * N2 * 3;
    float kx[KPT], ky[KPT], kz[KPT];
    int   kc[KPT];
    #pragma unroll
    for (int i = 0; i < KPT; ++i) {
        const int j = i * 1024 + t;      // 0..8191, coalesced per iter
        kx[i] = kb[j * 3 + 0];
        ky[i] = kb[j * 3 + 1];
        kz[i] = kb[j * 3 + 2];
        kc[i] = (cell_of(kx[i]) * GC + cell_of(ky[i])) * GC + cell_of(kz[i]);
        atomicAdd(&h8[g][kc[i]], 1);
    }
    __syncthreads();

    // ---- reduce privatized hists, inclusive Hillis-Steele scan ----
    int total = 0;
    if (t < NCELL) {
        #pragma unroll
        for (int i = 0; i < NHIST; ++i) total += h8[i][t];
    }
    if (t < 128) sbuf[t] = total;
    __syncthreads();
    for (int off = 1; off < 128; off <<= 1) {
        int v = 0;
        if (t < 128 && t >= off) v = sbuf[t - off];
        __syncthreads();
        if (t < 128) sbuf[t] += v;
        __syncthreads();
    }
    if (t < NCELL) {
        cursor[t] = sbuf[t] - total;               // exclusive cell start
        cell_start[b * (NCELL + 1) + t + 1] = sbuf[t];
        if (t == 0) cell_start[b * (NCELL + 1)] = 0;
    }
    __syncthreads();

    // ---- claim final slots (LDS atomics; within-cell order arbitrary,
    //      the query bitmap restores original-index order) ----
    int slot[KPT];
    #pragma unroll
    for (int i = 0; i < KPT; ++i)
        slot[i] = atomicAdd(&cursor[kc[i]], 1);
    __syncthreads();

    // ---- staged output: 4 passes, each emits one contiguous 2048-run
    //      coalesced (R5's scattered 16B global stores were the bottleneck).
    float4* sb = sorted + (size_t)b * N2;
    #pragma unroll
    for (int p = 0; p < N2 / CHUNK; ++p) {
        #pragma unroll
        for (int i = 0; i < KPT; ++i) {
            if ((slot[i] >> 11) == p) {            // CHUNK = 2048 = 1<<11
                float4 v;
                v.x = kx[i]; v.y = ky[i]; v.z = kz[i];
                v.w = __int_as_float(i * 1024 + t);// original key id
                stage[slot[i] & (CHUNK - 1)] = v;
            }
        }
        __syncthreads();
        const int base = p * CHUNK;
        #pragma unroll
        for (int r = 0; r < CHUNK / 1024; ++r)
            sb[base + r * 1024 + t] = stage[r * 1024 + t];
        __syncthreads();
    }
}

// ---------------- pass 2: per-query grid scan (verified R0 body) -----------
__global__ __launch_bounds__(256) void ballquery_grid_kernel(
    const float* __restrict__ query,        // [B*N1, 3]
    const float4* __restrict__ sorted,      // [B*N2] grouped by cell
    const int* __restrict__ cell_start,     // [B, 126]
    int* __restrict__ out)                  // [B*N1, K]
{
    __shared__ unsigned int bm[4 * 256];    // 4 waves x 8192-bit bitmap

    const int lane = threadIdx.x & 63;
    const int wv   = threadIdx.x >> 6;
    const int q    = blockIdx.x * 4 + wv;   // 0 .. B*N1-1
    const int b    = q >> 11;

    const float qx = query[q * 3 + 0];
    const float qy = query[q * 3 + 1];
    const float qz = query[q * 3 + 2];

    // Octant of cells the ball can touch (cell = 2r, so +/-1 on the near side).
    const float ux = qx * INVCELL, uy = qy * INVCELL, uz = qz * INVCELL;
    const int cx = cell_of(qx), cy = cell_of(qy), cz = cell_of(qz);
    const int nx = (ux - cx < 0.5f) ? cx - 1 : cx + 1;
    const int ny = (uy - cy < 0.5f) ? cy - 1 : cy + 1;
    const int nz = (uz - cz < 0.5f) ? cz - 1 : cz + 1;
    const int xlo = max(0, min(cx, nx)), xhi = min(GC - 1, max(cx, nx));
    const int ylo = max(0, min(cy, ny)), yhi = min(GC - 1, max(cy, ny));
    const int zlo = max(0, min(cz, nz)), zhi = min(GC - 1, max(cz, nz));

    unsigned int* wbm = bm + wv * 256;
    uint4 zz; zz.x = zz.y = zz.z = zz.w = 0u;
    ((uint4*)wbm)[lane] = zz;               // clear bitmap (ds_write_b128)

    const int*    cs = cell_start + b * (NCELL + 1);
    const float4* sb = sorted + (size_t)b * N2;

    for (int xx = xlo; xx <= xhi; ++xx) {
        for (int yy = ylo; yy <= yhi; ++yy) {
            const int colz = (xx * GC + yy) * GC;
            const int s = cs[colz + zlo];
            const int e = cs[colz + zhi + 1];          // z-cells are contiguous
            for (int t0 = s; t0 < e; t0 += 64) {
                const int i = t0 + lane;
                const float4 kv = sb[min(i, e - 1)];
                const float dx = kv.x - qx;
                const float dy = kv.y - qy;
                const float dz = kv.z - qz;
                const bool within = (i < e) && (dx * dx + dy * dy + dz * dz < R2);
                if (within) {
                    const int id = __float_as_int(kv.w);
                    atomicOr(&wbm[id >> 5], 1u << (id & 31));
                }
            }
        }
    }

    // ---- extraction: lane owns original-index range [128*lane, 128*lane+128)
    const uint4 w = ((const uint4*)wbm)[lane];
    const int c = __popc(w.x) + __popc(w.y) + __popc(w.z) + __popc(w.w);

    // inclusive wave prefix sum of c
    int x = c;
    #pragma unroll
    for (int off = 1; off < 64; off <<= 1) {
        int y = __shfl_up(x, off);
        if (lane >= off) x += y;
    }
    const int base = x - c;
    const int cnt  = __shfl(x, 63);

    // first set bit overall (0 if none)
    int fs;
    if      (w.x) fs = __builtin_ctz(w.x);
    else if (w.y) fs = 32 + __builtin_ctz(w.y);
    else if (w.z) fs = 64 + __builtin_ctz(w.z);
    else if (w.w) fs = 96 + __builtin_ctz(w.w);
    else          fs = 0;
    int myfirst = c ? (lane << 7) + fs : 0x7fffffff;
    #pragma unroll
    for (int off = 32; off; off >>= 1)
        myfirst = min(myfirst, __shfl_xor(myfirst, off));
    const int firstIdx = (cnt == 0) ? 0 : myfirst;

    // emit set bits in order
    int* op = out + q * K;
    int slot = base;
    unsigned int wr[4] = {w.x, w.y, w.z, w.w};
    #pragma unroll
    for (int r = 0; r < 4; ++r) {
        unsigned int m = wr[r];
        const int bb = (lane << 7) + (r << 5);
        while (m) {
            const int bp = __builtin_ctz(m);
            m &= m - 1;
            if (slot < K) op[slot] = bb + bp;
            ++slot;
        }
    }

    // pad remaining slots with firstIdx
    const int kpad = cnt < K ? cnt : K;
    const int s2 = kpad + lane;
    if (s2 < K) op[s2] = firstIdx;
}

// ---------------- fallback (ws too small): brute force (R4-verified) -------
__global__ __launch_bounds__(256) void bq_brute2_kernel(
    const float* __restrict__ query, const float* __restrict__ key,
    int* __restrict__ out)
{
    const int lane = threadIdx.x & 63;
    const int w    = blockIdx.x * 4 + (threadIdx.x >> 6);
    const int q0   = w * 2;
    const int q1   = q0 + 1;
    const int b    = q0 >> 11;

    const float qx0 = query[q0 * 3 + 0], qy0 = query[q0 * 3 + 1], qz0 = query[q0 * 3 + 2];
    const float qx1 = query[q1 * 3 + 0], qy1 = query[q1 * 3 + 1], qz1 = query[q1 * 3 + 2];

    const float* kb = key + (size_t)b * N2 * 3;
    const unsigned long long below = (lane == 0) ? 0ull : (~0ull >> (64 - lane));

    int cnt0 = 0, cnt1 = 0, f0 = -1, f1 = -1;
    int* op0 = out + (size_t)q0 * K;
    int* op1 = out + (size_t)q1 * K;

    #pragma unroll 4
    for (int c = 0; c < N2 / 64; ++c) {
        const int j = (c << 6) + lane;
        const float x = kb[j * 3 + 0];
        const float y = kb[j * 3 + 1];
        const float z = kb[j * 3 + 2];
        {
            const float dx = x - qx0, dy = y - qy0, dz = z - qz0;
            const bool within = dx * dx + dy * dy + dz * dz < R2;
            const unsigned long long m = __ballot(within);
            if (m) {
                if (f0 < 0) f0 = (c << 6) + __builtin_ctzll(m);
                if (within) {
                    const int slot = cnt0 + __popcll(m & below);
                    if (slot < K) op0[slot] = j;
                }
                cnt0 += __popcll(m);
            }
        }
        {
            const float dx = x - qx1, dy = y - qy1, dz = z - qz1;
            const bool within = dx * dx + dy * dy + dz * dz < R2;
            const unsigned long long m = __ballot(within);
            if (m) {
                if (f1 < 0) f1 = (c << 6) + __builtin_ctzll(m);
                if (within) {
                    const int slot = cnt1 + __popcll(m & below);
                    if (slot < K) op1[slot] = j;
                }
                cnt1 += __popcll(m);
            }
        }
    }

    const int first0 = (f0 < 0) ? 0 : f0;
    const int first1 = (f1 < 0) ? 0 : f1;
    const int c0 = cnt0 < K ? cnt0 : K;
    const int c1 = cnt1 < K ? cnt1 : K;
    if (c0 + lane < K) op0[c0 + lane] = first0;
    if (c1 + lane < K) op1[c1 + lane] = first1;
}

extern "C" void kernel_launch(void* const* d_in, const int* in_sizes, int n_in,
                              void* d_out, int out_size, void* d_ws, size_t ws_size,
                              hipStream_t stream) {
    const float* query = (const float*)d_in[0];   // B*N1*3 floats
    const float* key   = (const float*)d_in[1];   // B*N2*3 floats
    int* out = (int*)d_out;                       // B*N1*K int32

    if (ws_size < WS_NEEDED) {
        bq_brute2_kernel<<<(B * N1) / 8, 256, 0, stream>>>(query, key, out);
        return;
    }

    float4* sorted     = (float4*)d_ws;
    int*    cell_start = (int*)((char*)d_ws + SORTED_BYTES);

    build_kernel<<<B, 1024, 0, stream>>>(key, cell_start, sorted);
    ballquery_grid_kernel<<<(B * N1) / 4, 256, 0, stream>>>(query, sorted, cell_start, out);
}